// Round 9
// baseline (113.543 us; speedup 1.0000x reference)
//
#include <hip/hip_runtime.h>
#include <hip/hip_bf16.h>
#include <stdint.h>

typedef float f32x4 __attribute__((ext_vector_type(4)));
typedef short short4v __attribute__((ext_vector_type(4)));
typedef short short8 __attribute__((ext_vector_type(8)));
typedef __bf16 bf16x8 __attribute__((ext_vector_type(8)));

#define D_MODEL 512
#define MAX_LEN 1024
#define M_TOTAL 65536

static __device__ __forceinline__ short f2bf(float f) {
  union { __hip_bfloat16 h; short s; } u;
  u.h = __float2bfloat16(f);
  return u.s;
}

static __device__ __forceinline__ bf16x8 as_bf16x8(short8 s) {
  union { short8 s; bf16x8 b; } u;
  u.s = s;
  return u.b;
}

// async global->LDS, 16B per lane. LDS dest must be wave-uniform base + lane*16.
static __device__ __forceinline__ void gload_lds16(const void* g, void* l) {
  __builtin_amdgcn_global_load_lds(
      (const __attribute__((address_space(1))) uint32_t*)(uintptr_t)g,
      (__attribute__((address_space(3))) uint32_t*)(uint32_t)(uintptr_t)l,
      16, 0, 0);
}

static __device__ __forceinline__ void mfma_bf16(f32x4& c, short8 a, short8 b) {
  asm("v_mfma_f32_16x16x32_bf16 %0, %1, %2, %0" : "+v"(c) : "v"(a), "v"(b));
}

// ---------------- prep: W [1024][512] f32 -> WtopT / WbotT [512][512] bf16 ([n][k]) ----
__global__ __launch_bounds__(256) void prep_w_kernel(const float* __restrict__ W,
                                                     short* __restrict__ WtT,
                                                     short* __restrict__ WbT) {
  __shared__ float tile[64][65];
  const int t = threadIdx.x;
  const int nt = blockIdx.x * 64;   // n tile in [0,512)
  const int kt = blockIdx.y * 64;   // k tile in [0,1024)
  const int c = t & 63;
  const int r0 = t >> 6;
#pragma unroll
  for (int r = r0; r < 64; r += 4)
    tile[r][c] = W[(size_t)(kt + r) * D_MODEL + nt + c];
  __syncthreads();
  short* dst = (kt < D_MODEL) ? WtT : WbT;
  const int kb = kt & (D_MODEL - 1);
#pragma unroll
  for (int n = r0; n < 64; n += 4)
    dst[(size_t)(nt + n) * D_MODEL + kb + c] = f2bf(tile[c][n]);
}

// ---------------- prep: encoding [1024][512] f32 -> bf16 (row-major) -------------------
__global__ __launch_bounds__(256) void prep_enc_kernel(const float* __restrict__ enc,
                                                       short* __restrict__ encb) {
  const int i = (blockIdx.x * 256 + threadIdx.x) * 4;
  float4 v = *reinterpret_cast<const float4*>(enc + i);
  short4 r = make_short4(f2bf(v.x), f2bf(v.y), f2bf(v.z), f2bf(v.w));
  *reinterpret_cast<short4*>(encb + i) = r;
}

// ---------------- GEMM1: encW[1024][512] = enc_bf16 @ WtopT^T (fp32 out) ---------------
__global__ __launch_bounds__(256) void gemm_encw_kernel(const short* __restrict__ A,
                                                        const short* __restrict__ BT,
                                                        float* __restrict__ C) {
  __shared__ short As[128 * 32];
  __shared__ short Bs[128 * 32];
  const int t = threadIdx.x;
  const int lane = t & 63;
  const int wave = t >> 6;
  const int wm = wave >> 1, wn = wave & 1;
  const int m0 = blockIdx.y * 128, n0 = blockIdx.x * 128;
  const int koff = (t & 3) * 8;
  const int rr = t >> 2;
  const int l15 = lane & 15, lk = (lane >> 4) * 8;
  f32x4 acc[4][4] = {};
  for (int kt = 0; kt < D_MODEL; kt += 32) {
    __syncthreads();
    gload_lds16(A + (size_t)(m0 + rr) * D_MODEL + kt + koff, (char*)As + t * 16);
    gload_lds16(A + (size_t)(m0 + 64 + rr) * D_MODEL + kt + koff, (char*)As + 4096 + t * 16);
    gload_lds16(BT + (size_t)(n0 + rr) * D_MODEL + kt + koff, (char*)Bs + t * 16);
    gload_lds16(BT + (size_t)(n0 + 64 + rr) * D_MODEL + kt + koff, (char*)Bs + 4096 + t * 16);
    __syncthreads();
    short8 af[4], bfr[4];
#pragma unroll
    for (int mi = 0; mi < 4; ++mi)
      af[mi] = *reinterpret_cast<const short8*>(&As[(wm * 64 + mi * 16 + l15) * 32 + lk]);
#pragma unroll
    for (int ni = 0; ni < 4; ++ni)
      bfr[ni] = *reinterpret_cast<const short8*>(&Bs[(wn * 64 + ni * 16 + l15) * 32 + lk]);
#pragma unroll
    for (int mi = 0; mi < 4; ++mi)
#pragma unroll
      for (int ni = 0; ni < 4; ++ni)
        mfma_bf16(acc[mi][ni], af[mi], bfr[ni]);
  }
#pragma unroll
  for (int mi = 0; mi < 4; ++mi)
#pragma unroll
    for (int r = 0; r < 4; ++r) {
      const int row = m0 + wm * 64 + mi * 16 + (lane >> 4) * 4 + r;
#pragma unroll
      for (int ni = 0; ni < 4; ++ni) {
        const int col = n0 + wn * 64 + ni * 16 + l15;
        C[(size_t)row * D_MODEL + col] = acc[mi][ni][r];
      }
    }
}

// ---------------- GEMM2: out = latent @ WbotT^T + encW[dfn] + encW[dfa] + b ------------
// BM=BN=128, BK=64, XOR-swizzled LDS, XCD-chunked map, double-buffered LDS.
// KEY CHANGE vs r8: NO global_load_lds and NO global stores inside the K-loop.
// Both A and B are staged global->reg (depth-2 prefetch) -> cvt/ds_write.
// The __syncthreads release fence then only needs lgkmcnt(0) (ds_writes);
// plain global->reg loads stay in flight ACROSS barriers, so tile t+2's loads
// complete during step t+1 and are consumed by WRITE at step t+1 with zero stall.
__global__ __launch_bounds__(256, 2) void gemm_main_kernel(
    const float* __restrict__ latent,   // [65536][512] f32
    const short* __restrict__ BT,       // WbotT [512][512] bf16 ([n][k])
    const float* __restrict__ encW,     // [1024][512] f32
    const int* __restrict__ dfn,
    const int* __restrict__ dfa,
    const float* __restrict__ bias,     // [512]
    float* __restrict__ out) {          // [65536][512] f32
  __shared__ alignas(16) short As0[128 * 64];
  __shared__ alignas(16) short As1[128 * 64];
  __shared__ alignas(16) short Bs0[128 * 64];
  __shared__ alignas(16) short Bs1[128 * 64];
  const int t = threadIdx.x;
  const int lane = t & 63;
  const int wave = t >> 6;
  const int wm = wave >> 1, wn = wave & 1;

  // XCD-chunked mapping: xcd = bid&7 owns m-panels [xcd*64, xcd*64+64);
  // 4 n-blocks of each m-panel consecutive -> same-XCD L2 reuse of A.
  const int bid = blockIdx.x;
  const int slot = bid >> 3;
  const int mblk = (bid & 7) * 64 + (slot >> 2);
  const int nblk = slot & 3;
  const int m0 = mblk * 128, n0 = nblk * 128;

  // A staging (coalesced): row j*16 + (t>>4), f32 cols (t&15)*4..+4.
  const int rowA = t >> 4;
  const int wbyteA = ((t & 15) * 8) ^ ((rowA & 7) << 4);  // swizzled byte-in-row
  // B staging (coalesced, linear global): chunk c: row rB = c*32 + (t>>3), slot t&7.
  const int rbB = t >> 3;
  const int swByteB = (((t & 7) ^ (rbB & 7)) * 16);       // swizzled byte-in-row

  const int l15 = lane & 15;
  const int lsl = lane >> 4;   // k sub-slot 0..3

  const float* aBase = latent + (size_t)(m0 + rowA) * D_MODEL + (t & 15) * 4;
  const short* bBase[4];
#pragma unroll
  for (int c = 0; c < 4; ++c)
    bBase[c] = BT + (size_t)(n0 + c * 32 + rbB) * D_MODEL + (t & 7) * 8;

  f32x4 acc[4][4] = {};
  f32x4 av0[8], av1[8];     // A-tile prefetch regs (parity = tile & 1)
  short8 bv0[4], bv1[4];    // B-tile prefetch regs

  // ---- helpers (macros keep every LDS address compile-time static) ----
#define LOAD_A(KO, AV)                                                      \
  {                                                                         \
    _Pragma("unroll") for (int j = 0; j < 8; ++j)                           \
        (AV)[j] = *reinterpret_cast<const f32x4*>(aBase + (size_t)j * 16 * D_MODEL + (KO)); \
  }
#define LOAD_B(KO, BV)                                                      \
  {                                                                         \
    _Pragma("unroll") for (int c = 0; c < 4; ++c)                           \
        (BV)[c] = *reinterpret_cast<const short8*>(bBase[c] + (KO));        \
  }
#define WRITE_A(AV, ADST)                                                   \
  {                                                                         \
    _Pragma("unroll") for (int j = 0; j < 8; ++j) {                         \
      short4v h;                                                            \
      h[0] = f2bf((AV)[j][0]); h[1] = f2bf((AV)[j][1]);                     \
      h[2] = f2bf((AV)[j][2]); h[3] = f2bf((AV)[j][3]);                     \
      *reinterpret_cast<short4v*>((char*)(ADST) + (j * 16 + rowA) * 128 + wbyteA) = h; \
    }                                                                       \
  }
#define WRITE_B(BV, BDST)                                                   \
  {                                                                         \
    _Pragma("unroll") for (int c = 0; c < 4; ++c)                           \
        *reinterpret_cast<short8*>((char*)(BDST) + (c * 32 + rbB) * 128 + swByteB) = (BV)[c]; \
  }
#define COMPUTE(ASRC, BSRC)                                                 \
  {                                                                         \
    _Pragma("unroll") for (int kk = 0; kk < 2; ++kk) {                      \
      bf16x8 af[4], bfv[4];                                                 \
      _Pragma("unroll") for (int mi = 0; mi < 4; ++mi) {                    \
        const int r = wm * 64 + mi * 16 + l15;                              \
        const int s = (kk * 4 + lsl) ^ (r & 7);                             \
        af[mi] = as_bf16x8(                                                 \
            *reinterpret_cast<const short8*>((char*)(ASRC) + r * 128 + s * 16)); \
      }                                                                     \
      _Pragma("unroll") for (int ni = 0; ni < 4; ++ni) {                    \
        const int r = wn * 64 + ni * 16 + l15;                              \
        const int s = (kk * 4 + lsl) ^ (r & 7);                             \
        bfv[ni] = as_bf16x8(                                                \
            *reinterpret_cast<const short8*>((char*)(BSRC) + r * 128 + s * 16)); \
      }                                                                     \
      _Pragma("unroll") for (int mi = 0; mi < 4; ++mi)                      \
          _Pragma("unroll") for (int ni = 0; ni < 4; ++ni)                  \
              acc[mi][ni] = __builtin_amdgcn_mfma_f32_16x16x32_bf16(        \
                  af[mi], bfv[ni], acc[mi][ni], 0, 0, 0);                   \
    }                                                                       \
  }

  // ---- prologue: tiles 0,1 into regs; tile 0 into LDS buffer 0 ----
  LOAD_A(0, av0);
  LOAD_B(0, bv0);
  LOAD_A(64, av1);
  LOAD_B(64, bv1);
  WRITE_A(av0, As0);
  WRITE_B(bv0, Bs0);
  __syncthreads();

  // ---- main loop: 8 K-steps (tiles 0..7), fully unrolled, static buffers ----
#pragma unroll
  for (int tt = 0; tt < 8; ++tt) {
    short* Acur = (tt & 1) ? As1 : As0;
    short* Bcur = (tt & 1) ? Bs1 : Bs0;
    short* Anxt = (tt & 1) ? As0 : As1;
    short* Bnxt = (tt & 1) ? Bs0 : Bs1;
    // issue loads for tile tt+2 into the parity reg slot freed at step tt-1's WRITE
    if (tt < 6) {
      f32x4(&la)[8] = (tt & 1) ? av1 : av0;
      short8(&lb)[4] = (tt & 1) ? bv1 : bv0;
      LOAD_A((tt + 2) * 64, la);
      LOAD_B((tt + 2) * 64, lb);
    }
    // compute tile tt from LDS
    COMPUTE(Acur, Bcur);
    // convert+write tile tt+1 (its loads were issued a full step ago -> no stall)
    if (tt < 7) {
      f32x4(&wa)[8] = (tt & 1) ? av0 : av1;
      short8(&wb)[4] = (tt & 1) ? bv0 : bv1;
      WRITE_A(wa, Anxt);
      WRITE_B(wb, Bnxt);
      __syncthreads();   // release fence: lgkmcnt only (no VMEM->LDS, no global stores)
    }
  }

  // epilogue: fused gather of encW rows (2 MB, L2/L3-resident) + bias
#pragma unroll
  for (int mi = 0; mi < 4; ++mi) {
#pragma unroll
    for (int r = 0; r < 4; ++r) {
      const int row = m0 + wm * 64 + mi * 16 + lsl * 4 + r;
      const int d1 = dfn[row];
      const int d2 = dfa[row];
      const float* e1 = encW + (size_t)d1 * D_MODEL;
      const float* e2 = encW + (size_t)d2 * D_MODEL;
      const size_t ro = (size_t)row * D_MODEL;
#pragma unroll
      for (int ni = 0; ni < 4; ++ni) {
        const int col = n0 + wn * 64 + ni * 16 + l15;
        out[ro + col] = acc[mi][ni][r] + e1[col] + e2[col] + bias[col];
      }
    }
  }
#undef LOAD_A
#undef LOAD_B
#undef WRITE_A
#undef WRITE_B
#undef COMPUTE
}

extern "C" void kernel_launch(void* const* d_in, const int* in_sizes, int n_in,
                              void* d_out, int out_size, void* d_ws, size_t ws_size,
                              hipStream_t stream) {
  const int* dfn = (const int*)d_in[0];
  const int* dfa = (const int*)d_in[1];
  const float* latent = (const float*)d_in[2];
  const float* enc = (const float*)d_in[3];
  const float* W = (const float*)d_in[4];
  const float* bias = (const float*)d_in[5];
  float* out = (float*)d_out;

  // workspace layout (4 MB total)
  char* ws = (char*)d_ws;
  short* WtT  = (short*)(ws);                       // 512KB  [512][512] bf16
  short* WbT  = (short*)(ws + 512 * 1024);          // 512KB  [512][512] bf16
  short* encb = (short*)(ws + 1024 * 1024);         // 1MB    [1024][512] bf16
  float* encW = (float*)(ws + 2 * 1024 * 1024);     // 2MB    [1024][512] f32

  hipLaunchKernelGGL(prep_w_kernel, dim3(8, 16), dim3(256), 0, stream, W, WtT, WbT);
  hipLaunchKernelGGL(prep_enc_kernel, dim3(512), dim3(256), 0, stream, enc, encb);
  hipLaunchKernelGGL(gemm_encw_kernel, dim3(4, 8), dim3(256), 0, stream, encb, WtT, encW);
  hipLaunchKernelGGL(gemm_main_kernel, dim3(2048), dim3(256), 0, stream,
                     latent, WbT, encW, dfn, dfa, bias, out);
}

// Round 10
// 110.656 us; speedup vs baseline: 1.0261x; 1.0261x over previous
//
#include <hip/hip_runtime.h>
#include <hip/hip_bf16.h>
#include <stdint.h>

typedef float f32x4 __attribute__((ext_vector_type(4)));
typedef short short4v __attribute__((ext_vector_type(4)));
typedef short short8 __attribute__((ext_vector_type(8)));
typedef __bf16 bf16x8 __attribute__((ext_vector_type(8)));

#define D_MODEL 512
#define MAX_LEN 1024
#define M_TOTAL 65536

static __device__ __forceinline__ short f2bf(float f) {
  union { __hip_bfloat16 h; short s; } u;
  u.h = __float2bfloat16(f);
  return u.s;
}

static __device__ __forceinline__ bf16x8 as_bf16x8(short8 s) {
  union { short8 s; bf16x8 b; } u;
  u.s = s;
  return u.b;
}

// async global->LDS, 16B per lane. LDS dest must be wave-uniform base + lane*16.
static __device__ __forceinline__ void gload_lds16(const void* g, void* l) {
  __builtin_amdgcn_global_load_lds(
      (const __attribute__((address_space(1))) uint32_t*)(uintptr_t)g,
      (__attribute__((address_space(3))) uint32_t*)(uint32_t)(uintptr_t)l,
      16, 0, 0);
}

static __device__ __forceinline__ void mfma_bf16(f32x4& c, short8 a, short8 b) {
  asm("v_mfma_f32_16x16x32_bf16 %0, %1, %2, %0" : "+v"(c) : "v"(a), "v"(b));
}

// ---------------- prep: W [1024][512] f32 -> WtopT / WbotT [512][512] bf16 ([n][k]) ----
__global__ __launch_bounds__(256) void prep_w_kernel(const float* __restrict__ W,
                                                     short* __restrict__ WtT,
                                                     short* __restrict__ WbT) {
  __shared__ float tile[64][65];
  const int t = threadIdx.x;
  const int nt = blockIdx.x * 64;   // n tile in [0,512)
  const int kt = blockIdx.y * 64;   // k tile in [0,1024)
  const int c = t & 63;
  const int r0 = t >> 6;
#pragma unroll
  for (int r = r0; r < 64; r += 4)
    tile[r][c] = W[(size_t)(kt + r) * D_MODEL + nt + c];
  __syncthreads();
  short* dst = (kt < D_MODEL) ? WtT : WbT;
  const int kb = kt & (D_MODEL - 1);
#pragma unroll
  for (int n = r0; n < 64; n += 4)
    dst[(size_t)(nt + n) * D_MODEL + kb + c] = f2bf(tile[c][n]);
}

// ---------------- prep: encoding [1024][512] f32 -> bf16 (row-major) -------------------
__global__ __launch_bounds__(256) void prep_enc_kernel(const float* __restrict__ enc,
                                                       short* __restrict__ encb) {
  const int i = (blockIdx.x * 256 + threadIdx.x) * 4;
  float4 v = *reinterpret_cast<const float4*>(enc + i);
  short4 r = make_short4(f2bf(v.x), f2bf(v.y), f2bf(v.z), f2bf(v.w));
  *reinterpret_cast<short4*>(encb + i) = r;
}

// ---------------- GEMM1: encW[1024][512] = enc_bf16 @ WtopT^T (fp32 out) ---------------
__global__ __launch_bounds__(256) void gemm_encw_kernel(const short* __restrict__ A,
                                                        const short* __restrict__ BT,
                                                        float* __restrict__ C) {
  __shared__ short As[128 * 32];
  __shared__ short Bs[128 * 32];
  const int t = threadIdx.x;
  const int lane = t & 63;
  const int wave = t >> 6;
  const int wm = wave >> 1, wn = wave & 1;
  const int m0 = blockIdx.y * 128, n0 = blockIdx.x * 128;
  const int koff = (t & 3) * 8;
  const int rr = t >> 2;
  const int l15 = lane & 15, lk = (lane >> 4) * 8;
  f32x4 acc[4][4] = {};
  for (int kt = 0; kt < D_MODEL; kt += 32) {
    __syncthreads();
    gload_lds16(A + (size_t)(m0 + rr) * D_MODEL + kt + koff, (char*)As + t * 16);
    gload_lds16(A + (size_t)(m0 + 64 + rr) * D_MODEL + kt + koff, (char*)As + 4096 + t * 16);
    gload_lds16(BT + (size_t)(n0 + rr) * D_MODEL + kt + koff, (char*)Bs + t * 16);
    gload_lds16(BT + (size_t)(n0 + 64 + rr) * D_MODEL + kt + koff, (char*)Bs + 4096 + t * 16);
    __syncthreads();
    short8 af[4], bfr[4];
#pragma unroll
    for (int mi = 0; mi < 4; ++mi)
      af[mi] = *reinterpret_cast<const short8*>(&As[(wm * 64 + mi * 16 + l15) * 32 + lk]);
#pragma unroll
    for (int ni = 0; ni < 4; ++ni)
      bfr[ni] = *reinterpret_cast<const short8*>(&Bs[(wn * 64 + ni * 16 + l15) * 32 + lk]);
#pragma unroll
    for (int mi = 0; mi < 4; ++mi)
#pragma unroll
      for (int ni = 0; ni < 4; ++ni)
        mfma_bf16(acc[mi][ni], af[mi], bfr[ni]);
  }
#pragma unroll
  for (int mi = 0; mi < 4; ++mi)
#pragma unroll
    for (int r = 0; r < 4; ++r) {
      const int row = m0 + wm * 64 + mi * 16 + (lane >> 4) * 4 + r;
#pragma unroll
      for (int ni = 0; ni < 4; ++ni) {
        const int col = n0 + wn * 64 + ni * 16 + l15;
        C[(size_t)row * D_MODEL + col] = acc[mi][ni][r];
      }
    }
}

// ---------------- GEMM2: out = latent @ WbotT^T + encW[dfn] + encW[dfa] + b ------------
// r9 structure (BM=BN=128, BK=64, XOR-swizzled LDS, XCD-chunked map, all-reg staging,
// depth-2 prefetch, lgkm-only barriers) but with 512 THREADS / 8 WAVES (2x4 grid):
//  - per-wave acc 32 VGPR, per-thread staging halves -> depth-2 prefetch fits <128 VGPR
//  - 2 blocks/CU x 8 waves = 4 waves/SIMD: doubled latency hiding at same pipeline depth
__global__ __launch_bounds__(512, 4) void gemm_main_kernel(
    const float* __restrict__ latent,   // [65536][512] f32
    const short* __restrict__ BT,       // WbotT [512][512] bf16 ([n][k])
    const float* __restrict__ encW,     // [1024][512] f32
    const int* __restrict__ dfn,
    const int* __restrict__ dfa,
    const float* __restrict__ bias,     // [512]
    float* __restrict__ out) {          // [65536][512] f32
  __shared__ alignas(16) short As0[128 * 64];
  __shared__ alignas(16) short As1[128 * 64];
  __shared__ alignas(16) short Bs0[128 * 64];
  __shared__ alignas(16) short Bs1[128 * 64];
  const int t = threadIdx.x;
  const int lane = t & 63;
  const int wave = t >> 6;          // 0..7
  const int wm = wave >> 2;         // 0..1 (64 rows each)
  const int wn = wave & 3;          // 0..3 (32 cols each)

  // XCD-chunked mapping: xcd = bid&7 owns m-panels [xcd*64, xcd*64+64);
  // 4 n-blocks of each m-panel consecutive -> same-XCD L2 reuse of A.
  const int bid = blockIdx.x;
  const int slot = bid >> 3;
  const int mblk = (bid & 7) * 64 + (slot >> 2);
  const int nblk = slot & 3;
  const int m0 = mblk * 128, n0 = nblk * 128;

  // A staging (coalesced): pass j in 0..3: row = j*32 + (t>>4), f32 cols (t&15)*4..+4.
  const int rowA = t >> 4;                                 // 0..31
  const int wbyteA = ((t & 15) * 8) ^ ((rowA & 7) << 4);   // swizzled byte-in-row
  // B staging (coalesced, linear global): pass c in 0..1: row = c*64 + (t>>3), slot t&7.
  const int rbB = t >> 3;                                  // 0..63
  const int swByteB = (((t & 7) ^ (rbB & 7)) * 16);        // swizzled byte-in-row

  const int l15 = lane & 15;
  const int lsl = lane >> 4;   // k sub-slot 0..3

  const float* aBase = latent + (size_t)(m0 + rowA) * D_MODEL + (t & 15) * 4;
  const short* bBase[2];
#pragma unroll
  for (int c = 0; c < 2; ++c)
    bBase[c] = BT + (size_t)(n0 + c * 64 + rbB) * D_MODEL + (t & 7) * 8;

  f32x4 acc[4][2] = {};
  f32x4 av0[4], av1[4];     // A-tile prefetch regs (parity = tile & 1)
  short8 bv0[2], bv1[2];    // B-tile prefetch regs

  // ---- helpers (macros keep every LDS address compile-time static) ----
#define LOAD_A(KO, AV)                                                      \
  {                                                                         \
    _Pragma("unroll") for (int j = 0; j < 4; ++j)                           \
        (AV)[j] = *reinterpret_cast<const f32x4*>(aBase + (size_t)j * 32 * D_MODEL + (KO)); \
  }
#define LOAD_B(KO, BV)                                                      \
  {                                                                         \
    _Pragma("unroll") for (int c = 0; c < 2; ++c)                           \
        (BV)[c] = *reinterpret_cast<const short8*>(bBase[c] + (KO));        \
  }
#define WRITE_A(AV, ADST)                                                   \
  {                                                                         \
    _Pragma("unroll") for (int j = 0; j < 4; ++j) {                         \
      short4v h;                                                            \
      h[0] = f2bf((AV)[j][0]); h[1] = f2bf((AV)[j][1]);                     \
      h[2] = f2bf((AV)[j][2]); h[3] = f2bf((AV)[j][3]);                     \
      *reinterpret_cast<short4v*>((char*)(ADST) + (j * 32 + rowA) * 128 + wbyteA) = h; \
    }                                                                       \
  }
#define WRITE_B(BV, BDST)                                                   \
  {                                                                         \
    _Pragma("unroll") for (int c = 0; c < 2; ++c)                           \
        *reinterpret_cast<short8*>((char*)(BDST) + (c * 64 + rbB) * 128 + swByteB) = (BV)[c]; \
  }
#define COMPUTE(ASRC, BSRC)                                                 \
  {                                                                         \
    _Pragma("unroll") for (int kk = 0; kk < 2; ++kk) {                      \
      bf16x8 af[4], bfv[2];                                                 \
      _Pragma("unroll") for (int mi = 0; mi < 4; ++mi) {                    \
        const int r = wm * 64 + mi * 16 + l15;                              \
        const int s = (kk * 4 + lsl) ^ (r & 7);                             \
        af[mi] = as_bf16x8(                                                 \
            *reinterpret_cast<const short8*>((char*)(ASRC) + r * 128 + s * 16)); \
      }                                                                     \
      _Pragma("unroll") for (int ni = 0; ni < 2; ++ni) {                    \
        const int r = wn * 32 + ni * 16 + l15;                              \
        const int s = (kk * 4 + lsl) ^ (r & 7);                             \
        bfv[ni] = as_bf16x8(                                                \
            *reinterpret_cast<const short8*>((char*)(BSRC) + r * 128 + s * 16)); \
      }                                                                     \
      _Pragma("unroll") for (int mi = 0; mi < 4; ++mi)                      \
          _Pragma("unroll") for (int ni = 0; ni < 2; ++ni)                  \
              acc[mi][ni] = __builtin_amdgcn_mfma_f32_16x16x32_bf16(        \
                  af[mi], bfv[ni], acc[mi][ni], 0, 0, 0);                   \
    }                                                                       \
  }

  // ---- prologue: tiles 0,1 into regs; tile 0 into LDS buffer 0 ----
  LOAD_A(0, av0);
  LOAD_B(0, bv0);
  LOAD_A(64, av1);
  LOAD_B(64, bv1);
  WRITE_A(av0, As0);
  WRITE_B(bv0, Bs0);
  __syncthreads();

  // ---- main loop: 8 K-steps (tiles 0..7), fully unrolled, static buffers ----
#pragma unroll
  for (int tt = 0; tt < 8; ++tt) {
    short* Acur = (tt & 1) ? As1 : As0;
    short* Bcur = (tt & 1) ? Bs1 : Bs0;
    short* Anxt = (tt & 1) ? As0 : As1;
    short* Bnxt = (tt & 1) ? Bs0 : Bs1;
    // issue loads for tile tt+2 into the parity reg slot freed at step tt-1's WRITE
    if (tt < 6) {
      f32x4(&la)[4] = (tt & 1) ? av1 : av0;
      short8(&lb)[2] = (tt & 1) ? bv1 : bv0;
      LOAD_A((tt + 2) * 64, la);
      LOAD_B((tt + 2) * 64, lb);
    }
    // compute tile tt from LDS
    COMPUTE(Acur, Bcur);
    // convert+write tile tt+1 (its loads were issued a full step ago -> no stall)
    if (tt < 7) {
      f32x4(&wa)[4] = (tt & 1) ? av0 : av1;
      short8(&wb)[2] = (tt & 1) ? bv0 : bv1;
      WRITE_A(wa, Anxt);
      WRITE_B(wb, Bnxt);
      __syncthreads();   // release fence: lgkmcnt only (no VMEM->LDS, no global stores)
    }
  }

  // epilogue: fused gather of encW rows (2 MB, L2/L3-resident) + bias
#pragma unroll
  for (int mi = 0; mi < 4; ++mi) {
#pragma unroll
    for (int r = 0; r < 4; ++r) {
      const int row = m0 + wm * 64 + mi * 16 + lsl * 4 + r;
      const int d1 = dfn[row];
      const int d2 = dfa[row];
      const float* e1 = encW + (size_t)d1 * D_MODEL;
      const float* e2 = encW + (size_t)d2 * D_MODEL;
      const size_t ro = (size_t)row * D_MODEL;
#pragma unroll
      for (int ni = 0; ni < 2; ++ni) {
        const int col = n0 + wn * 32 + ni * 16 + l15;
        out[ro + col] = acc[mi][ni][r] + e1[col] + e2[col] + bias[col];
      }
    }
  }
#undef LOAD_A
#undef LOAD_B
#undef WRITE_A
#undef WRITE_B
#undef COMPUTE
}

extern "C" void kernel_launch(void* const* d_in, const int* in_sizes, int n_in,
                              void* d_out, int out_size, void* d_ws, size_t ws_size,
                              hipStream_t stream) {
  const int* dfn = (const int*)d_in[0];
  const int* dfa = (const int*)d_in[1];
  const float* latent = (const float*)d_in[2];
  const float* enc = (const float*)d_in[3];
  const float* W = (const float*)d_in[4];
  const float* bias = (const float*)d_in[5];
  float* out = (float*)d_out;

  // workspace layout (4 MB total)
  char* ws = (char*)d_ws;
  short* WtT  = (short*)(ws);                       // 512KB  [512][512] bf16
  short* WbT  = (short*)(ws + 512 * 1024);          // 512KB  [512][512] bf16
  short* encb = (short*)(ws + 1024 * 1024);         // 1MB    [1024][512] bf16
  float* encW = (float*)(ws + 2 * 1024 * 1024);     // 2MB    [1024][512] f32

  hipLaunchKernelGGL(prep_w_kernel, dim3(8, 16), dim3(256), 0, stream, W, WtT, WbT);
  hipLaunchKernelGGL(prep_enc_kernel, dim3(512), dim3(256), 0, stream, enc, encb);
  hipLaunchKernelGGL(gemm_encw_kernel, dim3(4, 8), dim3(256), 0, stream, encb, WtT, encW);
  hipLaunchKernelGGL(gemm_main_kernel, dim3(2048), dim3(512), 0, stream,
                     latent, WbT, encW, dfn, dfa, bias, out);
}